// Round 14
// baseline (5862.584 us; speedup 1.0000x reference)
//
#include <hip/hip_runtime.h>
#include <hip/hip_cooperative_groups.h>
#include <cstdint>
#include <cstring>
#include <vector>
#include <algorithm>

namespace cg = cooperative_groups;

// ---------------------------------------------------------------------------
// GRASPLayer round 14:
//  - GRU = round-12 structure (dwordx4 W loads, b128 LDS broadcasts) with
//    v_pk_fma_f32 FORCED via inline asm (r13 proved the builtin scalarizes).
//    Packed fma == two scalar fmas, same order -> hfin bit-identical to r12.
//  - km_coop: ONE grid.sync/iter. Centers LDS-resident; redundant per-block
//    update (deterministic, bit-identical across blocks); part/pcnt double-
//    buffered by iter parity; per-iter flag slots. Math verbatim.
// ---------------------------------------------------------------------------

namespace {
constexpr int Nn = 2048;
constexpr int Tt = 128;
constexpr int Dd = 256;
constexpr int Hh = 256;
constexpr int Kk = 12;
constexpr int MAXIT = 100;
}

struct IdxArgs { int v[Kk]; };

typedef float v2f __attribute__((ext_vector_type(2)));

__device__ __forceinline__ float sigm(float x) { return 1.0f / (1.0f + expf(-x)); }

// Force the packed-f32 FMA (default op_sel: lane-wise lo/hi).
#define PKFMA(A, X, W) \
  asm("v_pk_fma_f32 %0, %1, %2, %0" : "+v"(A) : "v"(X), "v"(W))
#define LO2(V) ((v2f){(V).x, (V).y})
#define HI2(V) ((v2f){(V).z, (V).w})

// ---------------------------------------------------------------------------
// Pack Wih/Whh [3*256 x 256] into pk[k4][g][c][4] (float4 = 4 adjacent k of
// column c), g in {ihr,ihz,ihn,hhr,hhz,hhn}.
__global__ __launch_bounds__(64) void pack_w(
    const float* __restrict__ Wih, const float* __restrict__ Whh,
    float* __restrict__ pk)
{
  const int j = blockIdx.x;            // 0..767 = w-row (g*256 + c)
  const int k4 = threadIdx.x;          // 0..63
  const int g = j >> 8, c = j & 255;
  float4 vih = *(const float4*)&Wih[(size_t)j * 256 + k4 * 4];
  float4 vhh = *(const float4*)&Whh[(size_t)j * 256 + k4 * 4];
  *(float4*)&pk[(((size_t)k4 * 6 + g) * 256 + c) * 4]       = vih;
  *(float4*)&pk[(((size_t)k4 * 6 + 3 + g) * 256 + c) * 4]   = vhh;
}

// ---------------------------------------------------------------------------
// 256 blocks x 512 threads; block owns 8 rows. Thread (cp, q) accumulates
// cols {cp, cp+128} over k-quarter q with asm-packed k-pair FMA. LDS tree
// combine; q==0 applies gates. Structure identical to round-12 PASS.
__global__ __launch_bounds__(512, 1) void gru_q(
    const float* __restrict__ x, const int* __restrict__ len,
    const float* __restrict__ pk,
    const float* __restrict__ bih, const float* __restrict__ bhh,
    float* __restrict__ hfin)
{
  __shared__ alignas(16) float xls[8][260];
  __shared__ alignas(16) float hls[8][260];
  __shared__ float4 pbuf[2][8][256];            // 64 KB combine buffer
  const int tid = threadIdx.x;
  const int cp = tid & 127;                     // columns cp, cp+128
  const int q  = tid >> 7;                      // k-quarter
  const int n0 = blockIdx.x * 8;
  const int C0 = cp, C1 = cp + 128;

  const float bir0 = bih[C0], bhr0 = bhh[C0];
  const float biz0 = bih[Hh + C0], bhz0 = bhh[Hh + C0];
  const float bin0 = bih[2 * Hh + C0], bhn0 = bhh[2 * Hh + C0];
  const float bir1 = bih[C1], bhr1 = bhh[C1];
  const float biz1 = bih[Hh + C1], bhz1 = bhh[Hh + C1];
  const float bin1 = bih[2 * Hh + C1], bhn1 = bhh[2 * Hh + C1];
  int L[8];
  #pragma unroll
  for (int r = 0; r < 8; ++r) L[r] = len[n0 + r];

  const int q16 = q * 16;
  const size_t cp4 = (size_t)cp * 4;

  if (tid < 256) {
    #pragma unroll
    for (int r = 0; r < 8; ++r) hls[r][tid] = 0.f;
  }

  for (int t = 0; t < Tt; ++t) {
    // stage x_t (512 float4, coalesced)
    {
      int row = tid >> 6, c4 = tid & 63;
      *(float4*)&xls[row][c4 * 4] =
          *(const float4*)&x[(size_t)(n0 + row) * (Tt * Dd) + (size_t)t * Dd + c4 * 4];
    }
    __syncthreads();   // orders x stage + hls updates + pbuf reuse

    // v2f accumulators: .x = even-k chain, .y = odd-k chain
    v2f aR[8][2] = {}, aZ[8][2] = {}, aXN[8][2] = {}, aHN[8][2] = {};

    // ---- phase A: gx partials over k-quarter (k ascending) ----
    #pragma unroll 1
    for (int i = 0; i < 16; ++i) {
      const int k4 = q16 + i;
      const float* pb = pk + (size_t)k4 * 6144 + cp4;
      float4 wr0 = *(const float4*)(pb);
      float4 wr1 = *(const float4*)(pb + 512);
      float4 wz0 = *(const float4*)(pb + 1024);
      float4 wz1 = *(const float4*)(pb + 1536);
      float4 wn0 = *(const float4*)(pb + 2048);
      float4 wn1 = *(const float4*)(pb + 2560);
      const int k = k4 * 4;
      #pragma unroll
      for (int r = 0; r < 8; ++r) {
        float4 xv = *(const float4*)&xls[r][k];   // broadcast
        v2f xlo = LO2(xv), xhi = HI2(xv);
        PKFMA(aR[r][0],  xlo, LO2(wr0)); PKFMA(aR[r][0],  xhi, HI2(wr0));
        PKFMA(aR[r][1],  xlo, LO2(wr1)); PKFMA(aR[r][1],  xhi, HI2(wr1));
        PKFMA(aZ[r][0],  xlo, LO2(wz0)); PKFMA(aZ[r][0],  xhi, HI2(wz0));
        PKFMA(aZ[r][1],  xlo, LO2(wz1)); PKFMA(aZ[r][1],  xhi, HI2(wz1));
        PKFMA(aXN[r][0], xlo, LO2(wn0)); PKFMA(aXN[r][0], xhi, HI2(wn0));
        PKFMA(aXN[r][1], xlo, LO2(wn1)); PKFMA(aXN[r][1], xhi, HI2(wn1));
      }
    }
    // ---- phase B: gh partials over k-quarter ----
    #pragma unroll 1
    for (int i = 0; i < 16; ++i) {
      const int k4 = q16 + i;
      const float* pb = pk + (size_t)k4 * 6144 + 3072 + cp4;
      float4 wr0 = *(const float4*)(pb);
      float4 wr1 = *(const float4*)(pb + 512);
      float4 wz0 = *(const float4*)(pb + 1024);
      float4 wz1 = *(const float4*)(pb + 1536);
      float4 wn0 = *(const float4*)(pb + 2048);
      float4 wn1 = *(const float4*)(pb + 2560);
      const int k = k4 * 4;
      #pragma unroll
      for (int r = 0; r < 8; ++r) {
        float4 hv = *(const float4*)&hls[r][k];   // broadcast
        v2f hlo = LO2(hv), hhi = HI2(hv);
        PKFMA(aR[r][0],  hlo, LO2(wr0)); PKFMA(aR[r][0],  hhi, HI2(wr0));
        PKFMA(aR[r][1],  hlo, LO2(wr1)); PKFMA(aR[r][1],  hhi, HI2(wr1));
        PKFMA(aZ[r][0],  hlo, LO2(wz0)); PKFMA(aZ[r][0],  hhi, HI2(wz0));
        PKFMA(aZ[r][1],  hlo, LO2(wz1)); PKFMA(aZ[r][1],  hhi, HI2(wz1));
        PKFMA(aHN[r][0], hlo, LO2(wn0)); PKFMA(aHN[r][0], hhi, HI2(wn0));
        PKFMA(aHN[r][1], hlo, LO2(wn1)); PKFMA(aHN[r][1], hhi, HI2(wn1));
      }
    }

    // ---- fold even/odd-k lanes to scalars (identical to r12) ----
    float fR[8][2], fZ[8][2], fX[8][2], fH[8][2];
    #pragma unroll
    for (int r = 0; r < 8; ++r) {
      fR[r][0] = aR[r][0].x + aR[r][0].y;  fR[r][1] = aR[r][1].x + aR[r][1].y;
      fZ[r][0] = aZ[r][0].x + aZ[r][0].y;  fZ[r][1] = aZ[r][1].x + aZ[r][1].y;
      fX[r][0] = aXN[r][0].x + aXN[r][0].y; fX[r][1] = aXN[r][1].x + aXN[r][1].y;
      fH[r][0] = aHN[r][0].x + aHN[r][0].y; fH[r][1] = aHN[r][1].x + aHN[r][1].y;
    }

    // ---- combine tree: (q0+=q1, q2+=q3) then q0 += q2' ----
    if (q == 1 || q == 3) {
      const int reg = q >> 1;
      #pragma unroll
      for (int r = 0; r < 8; ++r) {
        pbuf[reg][r][C0] = make_float4(fR[r][0], fZ[r][0], fX[r][0], fH[r][0]);
        pbuf[reg][r][C1] = make_float4(fR[r][1], fZ[r][1], fX[r][1], fH[r][1]);
      }
    }
    __syncthreads();
    if (q == 0 || q == 2) {
      const int reg = q >> 1;
      #pragma unroll
      for (int r = 0; r < 8; ++r) {
        float4 p0 = pbuf[reg][r][C0];
        float4 p1 = pbuf[reg][r][C1];
        fR[r][0] += p0.x; fZ[r][0] += p0.y; fX[r][0] += p0.z; fH[r][0] += p0.w;
        fR[r][1] += p1.x; fZ[r][1] += p1.y; fX[r][1] += p1.z; fH[r][1] += p1.w;
      }
    }
    __syncthreads();
    if (q == 2) {
      #pragma unroll
      for (int r = 0; r < 8; ++r) {
        pbuf[0][r][C0] = make_float4(fR[r][0], fZ[r][0], fX[r][0], fH[r][0]);
        pbuf[0][r][C1] = make_float4(fR[r][1], fZ[r][1], fX[r][1], fH[r][1]);
      }
    }
    __syncthreads();

    // ---- gates (q==0 threads; order r,z,n, PyTorch layout) ----
    if (q == 0) {
      #pragma unroll
      for (int r = 0; r < 8; ++r) {
        if (t < L[r]) {
          float4 p0 = pbuf[0][r][C0];
          float4 p1 = pbuf[0][r][C1];
          float sR0 = fR[r][0] + p0.x, sZ0 = fZ[r][0] + p0.y;
          float sX0 = fX[r][0] + p0.z, sH0 = fH[r][0] + p0.w;
          float sR1 = fR[r][1] + p1.x, sZ1 = fZ[r][1] + p1.y;
          float sX1 = fX[r][1] + p1.z, sH1 = fH[r][1] + p1.w;
          float rg0 = sigm(sR0 + bir0 + bhr0);
          float zg0 = sigm(sZ0 + biz0 + bhz0);
          float ng0 = tanhf(sX0 + bin0 + rg0 * (sH0 + bhn0));
          float hv0 = (1.f - zg0) * ng0 + zg0 * hls[r][C0];
          float rg1 = sigm(sR1 + bir1 + bhr1);
          float zg1 = sigm(sZ1 + biz1 + bhz1);
          float ng1 = tanhf(sX1 + bin1 + rg1 * (sH1 + bhn1));
          float hv1 = (1.f - zg1) * ng1 + zg1 * hls[r][C1];
          hls[r][C0] = hv0;
          hls[r][C1] = hv1;
          if (t == L[r] - 1) {
            hfin[(size_t)(n0 + r) * Hh + C0] = hv0;
            hfin[(size_t)(n0 + r) * Hh + C1] = hv1;
          }
        }
      }
    }
    // next iteration's top __syncthreads orders hls/pbuf reuse
  }
}

// ---------------------------------------------------------------------------
// Cooperative kmeans, single grid.sync per iteration.
// 64 blocks x 256 threads, 32 rows/block (wave owns 8). Centers live in LDS;
// each block redundantly reduces all 64 partials in fixed order (bit-identical
// across blocks). part/pcnt double-buffered by iter parity (no 2nd sync
// needed). gflag[it] per-iter slots, pre-zeroed. Assign math verbatim r12.
__global__ __launch_bounds__(256, 1) void km_coop(
    const float* __restrict__ hfin, float* __restrict__ cent,
    float* __restrict__ part, int* __restrict__ pcnt,
    int* __restrict__ gflag, IdxArgs ia)
{
  __shared__ alignas(16) float rows_l[32][260];
  __shared__ alignas(16) float cs[Kk][260];
  __shared__ float psl[Kk][256];
  __shared__ float c2s[Kk];
  __shared__ int codes_l[32];
  __shared__ int pcl[Kk];
  __shared__ int cnt_s[Kk];
  __shared__ int chg_l, brk_l;
  cg::grid_group grid = cg::this_grid();
  const int tid = threadIdx.x, lane = tid & 63, w = tid >> 6;
  const int blk = blockIdx.x, n0 = blk * 32;

  #pragma unroll
  for (int i = 0; i < 8; ++i) {
    int f = tid + i * 256;
    int row = f >> 6, c4 = f & 63;
    *(float4*)&rows_l[row][c4 * 4] =
        *(const float4*)&hfin[(size_t)(n0 + row) * Hh + c4 * 4];
  }
  if (tid < 32) codes_l[tid] = -1;
  // initial centers -> LDS (all blocks, identical)
  #pragma unroll
  for (int i = 0; i < 3; ++i) {
    int f = tid + i * 256;
    int k = f >> 6, c4 = f & 63;
    *(float4*)&cs[k][c4 * 4] =
        *(const float4*)&hfin[(size_t)ia.v[k] * Hh + c4 * 4];
  }
  if (blk == 0 && tid < MAXIT) gflag[tid] = 0;   // per-iter flag slots
  __syncthreads();
  float4 v4[8];
  #pragma unroll
  for (int rr = 0; rr < 8; ++rr)
    v4[rr] = *(const float4*)&rows_l[w * 8 + rr][lane * 4];
  __threadfence();
  grid.sync();                                   // flags zeroed, everyone ready

  for (int it = 0; it < MAXIT; ++it) {
    if (tid == 0) chg_l = 0;
    if (tid < Kk) pcl[tid] = 0;
    __syncthreads();
    if (tid < Kk) {                              // serial |c|^2, verbatim order
      float s = 0.f;
      for (int c = 0; c < Hh; ++c) { float v = cs[tid][c]; s += v * v; }
      c2s[tid] = s;
    }
    __syncthreads();

    // assign (strict <: first-min = argmin), wave-parallel dot via shuffle
    int mych = 0;
    #pragma unroll
    for (int rr = 0; rr < 8; ++rr) {
      const int row = w * 8 + rr;
      float best = 3.4e38f; int bi = 0;
      #pragma unroll
      for (int k = 0; k < Kk; ++k) {
        float4 cv = *(const float4*)&cs[k][lane * 4];
        float p = v4[rr].x * cv.x + v4[rr].y * cv.y
                + v4[rr].z * cv.z + v4[rr].w * cv.w;
        #pragma unroll
        for (int m = 1; m < 64; m <<= 1) p += __shfl_xor(p, m, 64);
        float d = c2s[k] - 2.f * p;
        if (d < best) { best = d; bi = k; }
      }
      if (lane == 0) {
        if (bi != codes_l[row]) mych = 1;
        codes_l[row] = bi;
      }
    }
    if (mych) atomicOr(&chg_l, 1);
    __syncthreads();

    // per-column partial sums in fixed row order
    #pragma unroll
    for (int k = 0; k < Kk; ++k) psl[k][tid] = 0.f;
    for (int r = 0; r < 32; ++r)
      psl[codes_l[r]][tid] += rows_l[r][tid];
    if (tid < 32) atomicAdd(&pcl[codes_l[tid]], 1);
    if (tid == 0 && chg_l) atomicOr(&gflag[it], 1);
    __syncthreads();

    float* pb = part + (size_t)(it & 1) * (64 * Kk * Hh);
    int*   pc = pcnt + (it & 1) * (64 * Kk);
    #pragma unroll
    for (int k = 0; k < Kk; ++k)
      pb[((size_t)blk * Kk + k) * Hh + tid] = psl[k][tid];
    if (tid < Kk) pc[blk * Kk + tid] = pcl[tid];
    __threadfence();
    grid.sync();                                 // the ONLY sync this iter

    if (tid == 0) brk_l = atomicAdd(&gflag[it], 0);  // coherent read
    // redundant update: every block reduces all partials (fixed p order)
    if (tid < Kk) {
      int cn = 0;
      for (int p = 0; p < 64; ++p) cn += pc[p * Kk + tid];
      cnt_s[tid] = cn;
    }
    float sk[Kk];
    #pragma unroll
    for (int k = 0; k < Kk; ++k) {
      float s = 0.f;
      for (int p = 0; p < 64; ++p) s += pb[((size_t)p * Kk + k) * Hh + tid];
      sk[k] = s;
    }
    __syncthreads();                             // cnt_s + brk_l ready
    #pragma unroll
    for (int k = 0; k < Kk; ++k)
      if (cnt_s[k] > 0) cs[k][tid] = sk[k] / (float)cnt_s[k];
    __syncthreads();                             // cs consistent
    if (brk_l == 0) break;                       // Lloyd fixed point
  }

  // final centers -> global (block 0)
  if (blk == 0) {
    #pragma unroll
    for (int i = 0; i < 3; ++i) {
      int f = tid + i * 256;
      int k = f >> 6, c4 = f & 63;
      *(float4*)&cent[(size_t)k * Hh + c4 * 4] = *(const float4*)&cs[k][c4 * 4];
    }
  }
}

// ---------------------------------------------------------------------------
// h1 = relu(centers@g1_w + g1_b); h2 = relu(h1@g2_w + g2_b). One block.
__global__ __launch_bounds__(256) void gcn(
    const float* __restrict__ cent, const float* __restrict__ g1w,
    const float* __restrict__ g1b, const float* __restrict__ g2w,
    const float* __restrict__ g2b, float* __restrict__ h2out)
{
  __shared__ float a[Kk][Hh];
  __shared__ float b[Kk][Hh];
  int c = threadIdx.x;
  for (int i = c; i < Kk * Hh; i += 256) ((float*)a)[i] = cent[i];
  __syncthreads();
  float acc[Kk];
  #pragma unroll
  for (int k = 0; k < Kk; ++k) acc[k] = 0.f;
  for (int j = 0; j < Hh; ++j) {
    float wv = g1w[(size_t)j * Hh + c];
    #pragma unroll
    for (int k = 0; k < Kk; ++k) acc[k] += a[k][j] * wv;
  }
  #pragma unroll
  for (int k = 0; k < Kk; ++k) b[k][c] = fmaxf(acc[k] + g1b[c], 0.f);
  __syncthreads();
  #pragma unroll
  for (int k = 0; k < Kk; ++k) acc[k] = 0.f;
  for (int j = 0; j < Hh; ++j) {
    float wv = g2w[(size_t)j * Hh + c];
    #pragma unroll
    for (int k = 0; k < Kk; ++k) acc[k] += b[k][j] * wv;
  }
  #pragma unroll
  for (int k = 0; k < Kk; ++k) h2out[k * Hh + c] = fmaxf(acc[k] + g2b[c], 0.f);
}

// scores = softmax(relu(ht@centers^T)); clu = scores@h2; gated blend. 1 block/row.
__global__ __launch_bounds__(256) void finalk(
    const float* __restrict__ hfin, const float* __restrict__ cent,
    const float* __restrict__ h2, const float* __restrict__ w1w,
    const float* __restrict__ w1b, const float* __restrict__ w2w,
    const float* __restrict__ w2b, float* __restrict__ out)
{
  __shared__ alignas(16) float cs[Kk][Hh];
  __shared__ alignas(16) float hs[Kk][Hh];
  __shared__ float red[4];
  const int tid = threadIdx.x, lane = tid & 63, w = tid >> 6;
  const int n = blockIdx.x;
  for (int i = tid; i < Kk * Hh; i += 256) { ((float*)cs)[i] = cent[i]; ((float*)hs)[i] = h2[i]; }
  float ht = hfin[(size_t)n * Hh + tid];
  __syncthreads();

  auto bred = [&](float v) -> float {
    #pragma unroll
    for (int m = 1; m < 64; m <<= 1) v += __shfl_xor(v, m, 64);
    __syncthreads();
    if (lane == 0) red[w] = v;
    __syncthreads();
    return red[0] + red[1] + red[2] + red[3];
  };

  float ev[Kk];
  #pragma unroll
  for (int k = 0; k < Kk; ++k)
    ev[k] = fmaxf(bred(ht * cs[k][tid]), 0.f);

  float mx = ev[0];
  #pragma unroll
  for (int k = 1; k < Kk; ++k) mx = fmaxf(mx, ev[k]);
  float se = 0.f; float sc[Kk];
  #pragma unroll
  for (int k = 0; k < Kk; ++k) { sc[k] = expf(ev[k] - mx); se += sc[k]; }
  float inv = 1.f / se;
  float clu = 0.f;
  #pragma unroll
  for (int k = 0; k < Kk; ++k) clu += sc[k] * inv * hs[k][tid];

  float r1 = bred(clu * w1w[tid]);
  float r2 = bred(ht * w2w[tid]);
  float a1 = sigm(r1 + w1b[0]);
  float a2 = sigm(r2 + w2b[0]);
  float wn = a1 / (a1 + a2);
  out[(size_t)n * Hh + tid] = wn * clu + (1.f - wn) * ht;
}

// ---------------------------------------------------------------------------
// Host-side threefry2x32 (JAX), reproducing jax.random.permutation(key(42), 2048)[:12].
static void tf2x32(uint32_t k0, uint32_t k1, uint32_t c0, uint32_t c1,
                   uint32_t& o0, uint32_t& o1) {
  uint32_t ks2 = k0 ^ k1 ^ 0x1BD11BDAu;
  uint32_t x0 = c0 + k0, x1 = c1 + k1;
#define TFR(r) do { x0 += x1; x1 = (x1 << (r)) | (x1 >> (32 - (r))); x1 ^= x0; } while (0)
  TFR(13); TFR(15); TFR(26); TFR(6);
  x0 += k1;  x1 += ks2 + 1u;
  TFR(17); TFR(29); TFR(16); TFR(24);
  x0 += ks2; x1 += k0 + 2u;
  TFR(13); TFR(15); TFR(26); TFR(6);
  x0 += k0;  x1 += k1 + 3u;
  TFR(17); TFR(29); TFR(16); TFR(24);
  x0 += k1;  x1 += ks2 + 4u;
  TFR(13); TFR(15); TFR(26); TFR(6);
  x0 += ks2; x1 += k0 + 5u;
#undef TFR
  o0 = x0; o1 = x1;
}

static void compute_idx(int* out12) {
  uint32_t kh = 0u, kl = 42u;     // jax.random.key(42) -> (0, 42)
  std::vector<int> perm(Nn);
  for (int i = 0; i < Nn; ++i) perm[i] = i;
  std::vector<uint32_t> bits(Nn);
  std::vector<int> pos(Nn);
  for (int round = 0; round < 2; ++round) {     // 2 rounds for n=2048
    uint32_t nh, nl, sh, sl;
    tf2x32(kh, kl, 0u, 0u, nh, nl);             // split: counters (0,0),(0,1)
    tf2x32(kh, kl, 0u, 1u, sh, sl);
    kh = nh; kl = nl;
    // partitionable random_bits(32): bits[i] = o0 ^ o1 at counter (0, i)
    for (uint32_t i = 0; i < (uint32_t)Nn; ++i) {
      uint32_t o0, o1; tf2x32(sh, sl, 0u, i, o0, o1); bits[i] = o0 ^ o1;
    }
    for (int i = 0; i < Nn; ++i) pos[i] = i;
    std::stable_sort(pos.begin(), pos.end(),
                     [&](int a, int b) { return bits[a] < bits[b]; });
    std::vector<int> np(Nn);
    for (int i = 0; i < Nn; ++i) np[i] = perm[pos[i]];
    perm.swap(np);
  }
  for (int k = 0; k < Kk; ++k) out12[k] = perm[k];
}

// ---------------------------------------------------------------------------
extern "C" void kernel_launch(void* const* d_in, const int* in_sizes, int n_in,
                              void* d_out, int out_size, void* d_ws, size_t ws_size,
                              hipStream_t stream) {
  const float* x   = (const float*)d_in[0];
  const int*   len = (const int*)d_in[1];
  const float* Wih = (const float*)d_in[2];
  const float* Whh = (const float*)d_in[3];
  const float* bih = (const float*)d_in[4];
  const float* bhh = (const float*)d_in[5];
  const float* w1w = (const float*)d_in[6];
  const float* w1b = (const float*)d_in[7];
  const float* w2w = (const float*)d_in[8];
  const float* w2b = (const float*)d_in[9];
  const float* g1w = (const float*)d_in[10];
  const float* g1b = (const float*)d_in[11];
  const float* g2w = (const float*)d_in[12];
  const float* g2b = (const float*)d_in[13];
  float* out = (float*)d_out;

  float* wsf  = (float*)d_ws;
  float* hfin = wsf;                           // N*H
  float* cent = hfin + (size_t)Nn * Hh;        // K*H
  float* h2g  = cent + Kk * Hh;                // K*H
  float* part = h2g + Kk * Hh;                 // 2 * 64*K*H (parity dbuf)
  int*   pcnt = (int*)(part + 2 * 64 * Kk * Hh); // 2 * 64*K ints (pad 2048)
  int*   gflag = pcnt + 2048;                  // MAXIT ints
  float* pkw  = (float*)(gflag + 128);         // 393216 floats, 16B-aligned

  IdxArgs ia;
  compute_idx(ia.v);                           // host, deterministic, capture-safe

  pack_w<<<768, 64, 0, stream>>>(Wih, Whh, pkw);
  gru_q<<<256, 512, 0, stream>>>(x, len, pkw, bih, bhh, hfin);

  {
    void* ka[] = {(void*)&hfin, (void*)&cent, (void*)&part, (void*)&pcnt,
                  (void*)&gflag, (void*)&ia};
    hipLaunchCooperativeKernel((const void*)km_coop, dim3(64), dim3(256),
                               ka, 0, stream);
  }

  gcn<<<1, 256, 0, stream>>>(cent, g1w, g1b, g2w, g2b, h2g);
  finalk<<<Nn, 256, 0, stream>>>(hfin, cent, h2g, w1w, w1b, w2w, w2b, out);
}

// Round 15
// 5331.499 us; speedup vs baseline: 1.0996x; 1.0996x over previous
//
#include <hip/hip_runtime.h>
#include <hip/hip_cooperative_groups.h>
#include <cstdint>
#include <cstring>
#include <vector>
#include <algorithm>

namespace cg = cooperative_groups;

// ---------------------------------------------------------------------------
// GRASPLayer round 15:
//  - GRU verbatim from r14 PASS (3.36 ms plateau).
//  - km_coop reshaped: 16 blocks x 1024 threads (128 rows/block). Single
//    grid.sync/iter (r14-verified protocol), but partial-reduction traffic
//    drops 64x->16x blocks (50MB -> 3.1MB/iter) and the barrier spans 16
//    blocks. Summation order preserved (ascending global rows) -> centers
//    bit-identical -> absmax unchanged.
// ---------------------------------------------------------------------------

namespace {
constexpr int Nn = 2048;
constexpr int Tt = 128;
constexpr int Dd = 256;
constexpr int Hh = 256;
constexpr int Kk = 12;
constexpr int MAXIT = 100;
}

struct IdxArgs { int v[Kk]; };

typedef float v2f __attribute__((ext_vector_type(2)));

__device__ __forceinline__ float sigm(float x) { return 1.0f / (1.0f + expf(-x)); }

#define PKFMA(A, X, W) \
  asm("v_pk_fma_f32 %0, %1, %2, %0" : "+v"(A) : "v"(X), "v"(W))
#define LO2(V) ((v2f){(V).x, (V).y})
#define HI2(V) ((v2f){(V).z, (V).w})

// ---------------------------------------------------------------------------
// Pack Wih/Whh [3*256 x 256] into pk[k4][g][c][4] (float4 = 4 adjacent k of
// column c), g in {ihr,ihz,ihn,hhr,hhz,hhn}.
__global__ __launch_bounds__(64) void pack_w(
    const float* __restrict__ Wih, const float* __restrict__ Whh,
    float* __restrict__ pk)
{
  const int j = blockIdx.x;            // 0..767 = w-row (g*256 + c)
  const int k4 = threadIdx.x;          // 0..63
  const int g = j >> 8, c = j & 255;
  float4 vih = *(const float4*)&Wih[(size_t)j * 256 + k4 * 4];
  float4 vhh = *(const float4*)&Whh[(size_t)j * 256 + k4 * 4];
  *(float4*)&pk[(((size_t)k4 * 6 + g) * 256 + c) * 4]       = vih;
  *(float4*)&pk[(((size_t)k4 * 6 + 3 + g) * 256 + c) * 4]   = vhh;
}

// ---------------------------------------------------------------------------
// GRU (verbatim r14 PASS): 256 blocks x 512 threads; block owns 8 rows.
// Thread (cp, q) accumulates cols {cp, cp+128} over k-quarter q.
__global__ __launch_bounds__(512, 1) void gru_q(
    const float* __restrict__ x, const int* __restrict__ len,
    const float* __restrict__ pk,
    const float* __restrict__ bih, const float* __restrict__ bhh,
    float* __restrict__ hfin)
{
  __shared__ alignas(16) float xls[8][260];
  __shared__ alignas(16) float hls[8][260];
  __shared__ float4 pbuf[2][8][256];            // 64 KB combine buffer
  const int tid = threadIdx.x;
  const int cp = tid & 127;                     // columns cp, cp+128
  const int q  = tid >> 7;                      // k-quarter
  const int n0 = blockIdx.x * 8;
  const int C0 = cp, C1 = cp + 128;

  const float bir0 = bih[C0], bhr0 = bhh[C0];
  const float biz0 = bih[Hh + C0], bhz0 = bhh[Hh + C0];
  const float bin0 = bih[2 * Hh + C0], bhn0 = bhh[2 * Hh + C0];
  const float bir1 = bih[C1], bhr1 = bhh[C1];
  const float biz1 = bih[Hh + C1], bhz1 = bhh[Hh + C1];
  const float bin1 = bih[2 * Hh + C1], bhn1 = bhh[2 * Hh + C1];
  int L[8];
  #pragma unroll
  for (int r = 0; r < 8; ++r) L[r] = len[n0 + r];

  const int q16 = q * 16;
  const size_t cp4 = (size_t)cp * 4;

  if (tid < 256) {
    #pragma unroll
    for (int r = 0; r < 8; ++r) hls[r][tid] = 0.f;
  }

  for (int t = 0; t < Tt; ++t) {
    {
      int row = tid >> 6, c4 = tid & 63;
      *(float4*)&xls[row][c4 * 4] =
          *(const float4*)&x[(size_t)(n0 + row) * (Tt * Dd) + (size_t)t * Dd + c4 * 4];
    }
    __syncthreads();

    v2f aR[8][2] = {}, aZ[8][2] = {}, aXN[8][2] = {}, aHN[8][2] = {};

    #pragma unroll 1
    for (int i = 0; i < 16; ++i) {
      const int k4 = q16 + i;
      const float* pb = pk + (size_t)k4 * 6144 + cp4;
      float4 wr0 = *(const float4*)(pb);
      float4 wr1 = *(const float4*)(pb + 512);
      float4 wz0 = *(const float4*)(pb + 1024);
      float4 wz1 = *(const float4*)(pb + 1536);
      float4 wn0 = *(const float4*)(pb + 2048);
      float4 wn1 = *(const float4*)(pb + 2560);
      const int k = k4 * 4;
      #pragma unroll
      for (int r = 0; r < 8; ++r) {
        float4 xv = *(const float4*)&xls[r][k];
        v2f xlo = LO2(xv), xhi = HI2(xv);
        PKFMA(aR[r][0],  xlo, LO2(wr0)); PKFMA(aR[r][0],  xhi, HI2(wr0));
        PKFMA(aR[r][1],  xlo, LO2(wr1)); PKFMA(aR[r][1],  xhi, HI2(wr1));
        PKFMA(aZ[r][0],  xlo, LO2(wz0)); PKFMA(aZ[r][0],  xhi, HI2(wz0));
        PKFMA(aZ[r][1],  xlo, LO2(wz1)); PKFMA(aZ[r][1],  xhi, HI2(wz1));
        PKFMA(aXN[r][0], xlo, LO2(wn0)); PKFMA(aXN[r][0], xhi, HI2(wn0));
        PKFMA(aXN[r][1], xlo, LO2(wn1)); PKFMA(aXN[r][1], xhi, HI2(wn1));
      }
    }
    #pragma unroll 1
    for (int i = 0; i < 16; ++i) {
      const int k4 = q16 + i;
      const float* pb = pk + (size_t)k4 * 6144 + 3072 + cp4;
      float4 wr0 = *(const float4*)(pb);
      float4 wr1 = *(const float4*)(pb + 512);
      float4 wz0 = *(const float4*)(pb + 1024);
      float4 wz1 = *(const float4*)(pb + 1536);
      float4 wn0 = *(const float4*)(pb + 2048);
      float4 wn1 = *(const float4*)(pb + 2560);
      const int k = k4 * 4;
      #pragma unroll
      for (int r = 0; r < 8; ++r) {
        float4 hv = *(const float4*)&hls[r][k];
        v2f hlo = LO2(hv), hhi = HI2(hv);
        PKFMA(aR[r][0],  hlo, LO2(wr0)); PKFMA(aR[r][0],  hhi, HI2(wr0));
        PKFMA(aR[r][1],  hlo, LO2(wr1)); PKFMA(aR[r][1],  hhi, HI2(wr1));
        PKFMA(aZ[r][0],  hlo, LO2(wz0)); PKFMA(aZ[r][0],  hhi, HI2(wz0));
        PKFMA(aZ[r][1],  hlo, LO2(wz1)); PKFMA(aZ[r][1],  hhi, HI2(wz1));
        PKFMA(aHN[r][0], hlo, LO2(wn0)); PKFMA(aHN[r][0], hhi, HI2(wn0));
        PKFMA(aHN[r][1], hlo, LO2(wn1)); PKFMA(aHN[r][1], hhi, HI2(wn1));
      }
    }

    float fR[8][2], fZ[8][2], fX[8][2], fH[8][2];
    #pragma unroll
    for (int r = 0; r < 8; ++r) {
      fR[r][0] = aR[r][0].x + aR[r][0].y;  fR[r][1] = aR[r][1].x + aR[r][1].y;
      fZ[r][0] = aZ[r][0].x + aZ[r][0].y;  fZ[r][1] = aZ[r][1].x + aZ[r][1].y;
      fX[r][0] = aXN[r][0].x + aXN[r][0].y; fX[r][1] = aXN[r][1].x + aXN[r][1].y;
      fH[r][0] = aHN[r][0].x + aHN[r][0].y; fH[r][1] = aHN[r][1].x + aHN[r][1].y;
    }

    if (q == 1 || q == 3) {
      const int reg = q >> 1;
      #pragma unroll
      for (int r = 0; r < 8; ++r) {
        pbuf[reg][r][C0] = make_float4(fR[r][0], fZ[r][0], fX[r][0], fH[r][0]);
        pbuf[reg][r][C1] = make_float4(fR[r][1], fZ[r][1], fX[r][1], fH[r][1]);
      }
    }
    __syncthreads();
    if (q == 0 || q == 2) {
      const int reg = q >> 1;
      #pragma unroll
      for (int r = 0; r < 8; ++r) {
        float4 p0 = pbuf[reg][r][C0];
        float4 p1 = pbuf[reg][r][C1];
        fR[r][0] += p0.x; fZ[r][0] += p0.y; fX[r][0] += p0.z; fH[r][0] += p0.w;
        fR[r][1] += p1.x; fZ[r][1] += p1.y; fX[r][1] += p1.z; fH[r][1] += p1.w;
      }
    }
    __syncthreads();
    if (q == 2) {
      #pragma unroll
      for (int r = 0; r < 8; ++r) {
        pbuf[0][r][C0] = make_float4(fR[r][0], fZ[r][0], fX[r][0], fH[r][0]);
        pbuf[0][r][C1] = make_float4(fR[r][1], fZ[r][1], fX[r][1], fH[r][1]);
      }
    }
    __syncthreads();

    if (q == 0) {
      #pragma unroll
      for (int r = 0; r < 8; ++r) {
        if (t < L[r]) {
          float4 p0 = pbuf[0][r][C0];
          float4 p1 = pbuf[0][r][C1];
          float sR0 = fR[r][0] + p0.x, sZ0 = fZ[r][0] + p0.y;
          float sX0 = fX[r][0] + p0.z, sH0 = fH[r][0] + p0.w;
          float sR1 = fR[r][1] + p1.x, sZ1 = fZ[r][1] + p1.y;
          float sX1 = fX[r][1] + p1.z, sH1 = fH[r][1] + p1.w;
          float rg0 = sigm(sR0 + bir0 + bhr0);
          float zg0 = sigm(sZ0 + biz0 + bhz0);
          float ng0 = tanhf(sX0 + bin0 + rg0 * (sH0 + bhn0));
          float hv0 = (1.f - zg0) * ng0 + zg0 * hls[r][C0];
          float rg1 = sigm(sR1 + bir1 + bhr1);
          float zg1 = sigm(sZ1 + biz1 + bhz1);
          float ng1 = tanhf(sX1 + bin1 + rg1 * (sH1 + bhn1));
          float hv1 = (1.f - zg1) * ng1 + zg1 * hls[r][C1];
          hls[r][C0] = hv0;
          hls[r][C1] = hv1;
          if (t == L[r] - 1) {
            hfin[(size_t)(n0 + r) * Hh + C0] = hv0;
            hfin[(size_t)(n0 + r) * Hh + C1] = hv1;
          }
        }
      }
    }
  }
}

// ---------------------------------------------------------------------------
// Cooperative kmeans: 16 blocks x 1024 threads, 128 rows/block (wave owns 8).
// Single grid.sync/iter (r14-verified protocol): redundant per-block update
// (fixed-order, bit-identical), part/pcnt parity dbuf, per-iter flag slots.
// Global row summation order identical to the 32-row version.
__global__ __launch_bounds__(1024, 1) void km_coop(
    const float* __restrict__ hfin, float* __restrict__ cent,
    float* __restrict__ part, int* __restrict__ pcnt,
    int* __restrict__ gflag, IdxArgs ia)
{
  __shared__ alignas(16) float rows_l[128][260];   // 133.1 KB
  __shared__ alignas(16) float cs[Kk][260];        // 12.5 KB
  __shared__ float psl[Kk][256];                   // 12.3 KB
  __shared__ float c2s[Kk];
  __shared__ int codes_l[128];
  __shared__ int pcl[Kk];
  __shared__ int cnt_s[Kk];
  __shared__ int chg_l, brk_l;
  cg::grid_group grid = cg::this_grid();
  const int tid = threadIdx.x, lane = tid & 63, w = tid >> 6;   // w: 0..15
  const int blk = blockIdx.x, n0 = blk * 128;

  // rows -> LDS: 128 rows x 64 float4 = 8192 f4; 8 per thread
  #pragma unroll
  for (int i = 0; i < 8; ++i) {
    int f = tid + i * 1024;
    int row = f >> 6, c4 = f & 63;
    *(float4*)&rows_l[row][c4 * 4] =
        *(const float4*)&hfin[(size_t)(n0 + row) * Hh + c4 * 4];
  }
  if (tid < 128) codes_l[tid] = -1;
  if (tid < 768) {                       // initial centers -> LDS (all blocks)
    int k = tid >> 6, c4 = tid & 63;
    *(float4*)&cs[k][c4 * 4] =
        *(const float4*)&hfin[(size_t)ia.v[k] * Hh + c4 * 4];
  }
  if (blk == 0 && tid < MAXIT) gflag[tid] = 0;     // per-iter flag slots
  __syncthreads();
  float4 v4[8];                                    // wave w owns rows w*8..w*8+7
  #pragma unroll
  for (int rr = 0; rr < 8; ++rr)
    v4[rr] = *(const float4*)&rows_l[w * 8 + rr][lane * 4];
  __threadfence();
  grid.sync();

  for (int it = 0; it < MAXIT; ++it) {
    if (tid == 0) chg_l = 0;
    if (tid < Kk) pcl[tid] = 0;
    __syncthreads();
    if (tid < Kk) {                                // serial |c|^2, fixed order
      float s = 0.f;
      for (int c = 0; c < Hh; ++c) { float v = cs[tid][c]; s += v * v; }
      c2s[tid] = s;
    }
    __syncthreads();

    // assign (strict <: first-min = argmin), wave-parallel dot via shuffle
    int mych = 0;
    #pragma unroll
    for (int rr = 0; rr < 8; ++rr) {
      const int row = w * 8 + rr;
      float best = 3.4e38f; int bi = 0;
      #pragma unroll
      for (int k = 0; k < Kk; ++k) {
        float4 cv = *(const float4*)&cs[k][lane * 4];
        float p = v4[rr].x * cv.x + v4[rr].y * cv.y
                + v4[rr].z * cv.z + v4[rr].w * cv.w;
        #pragma unroll
        for (int m = 1; m < 64; m <<= 1) p += __shfl_xor(p, m, 64);
        float d = c2s[k] - 2.f * p;
        if (d < best) { best = d; bi = k; }
      }
      if (lane == 0) {
        if (bi != codes_l[row]) mych = 1;
        codes_l[row] = bi;
      }
    }
    if (mych) atomicOr(&chg_l, 1);
    __syncthreads();

    // per-column partial sums, ascending row order (threads 0..255)
    if (tid < 256) {
      #pragma unroll
      for (int k = 0; k < Kk; ++k) psl[k][tid] = 0.f;
      for (int r = 0; r < 128; ++r)
        psl[codes_l[r]][tid] += rows_l[r][tid];
    }
    if (tid < 128) atomicAdd(&pcl[codes_l[tid]], 1);
    if (tid == 0 && chg_l) atomicOr(&gflag[it], 1);
    __syncthreads();

    float* pb = part + (size_t)(it & 1) * (16 * Kk * Hh);
    int*   pc = pcnt + (it & 1) * (16 * Kk);
    for (int f = tid; f < Kk * 256; f += 1024) {
      int k = f >> 8, c = f & 255;
      pb[((size_t)blk * Kk + k) * Hh + c] = psl[k][c];
    }
    if (tid < Kk) pc[blk * Kk + tid] = pcl[tid];
    __threadfence();
    grid.sync();                                   // the ONLY sync this iter

    if (tid == 0) brk_l = atomicAdd(&gflag[it], 0);
    if (tid < Kk) {
      int cn = 0;
      for (int p = 0; p < 16; ++p) cn += pc[p * Kk + tid];
      cnt_s[tid] = cn;
    }
    float sk[Kk];
    if (tid < 256) {
      #pragma unroll
      for (int k = 0; k < Kk; ++k) {
        float s = 0.f;
        for (int p = 0; p < 16; ++p) s += pb[((size_t)p * Kk + k) * Hh + tid];
        sk[k] = s;
      }
    }
    __syncthreads();                               // cnt_s + brk_l ready
    if (tid < 256) {
      #pragma unroll
      for (int k = 0; k < Kk; ++k)
        if (cnt_s[k] > 0) cs[k][tid] = sk[k] / (float)cnt_s[k];
    }
    __syncthreads();                               // cs consistent
    if (brk_l == 0) break;                         // Lloyd fixed point
  }

  // final centers -> global (block 0)
  if (blk == 0 && tid < 768) {
    int k = tid >> 6, c4 = tid & 63;
    *(float4*)&cent[(size_t)k * Hh + c4 * 4] = *(const float4*)&cs[k][c4 * 4];
  }
}

// ---------------------------------------------------------------------------
// h1 = relu(centers@g1_w + g1_b); h2 = relu(h1@g2_w + g2_b). One block.
__global__ __launch_bounds__(256) void gcn(
    const float* __restrict__ cent, const float* __restrict__ g1w,
    const float* __restrict__ g1b, const float* __restrict__ g2w,
    const float* __restrict__ g2b, float* __restrict__ h2out)
{
  __shared__ float a[Kk][Hh];
  __shared__ float b[Kk][Hh];
  int c = threadIdx.x;
  for (int i = c; i < Kk * Hh; i += 256) ((float*)a)[i] = cent[i];
  __syncthreads();
  float acc[Kk];
  #pragma unroll
  for (int k = 0; k < Kk; ++k) acc[k] = 0.f;
  for (int j = 0; j < Hh; ++j) {
    float wv = g1w[(size_t)j * Hh + c];
    #pragma unroll
    for (int k = 0; k < Kk; ++k) acc[k] += a[k][j] * wv;
  }
  #pragma unroll
  for (int k = 0; k < Kk; ++k) b[k][c] = fmaxf(acc[k] + g1b[c], 0.f);
  __syncthreads();
  #pragma unroll
  for (int k = 0; k < Kk; ++k) acc[k] = 0.f;
  for (int j = 0; j < Hh; ++j) {
    float wv = g2w[(size_t)j * Hh + c];
    #pragma unroll
    for (int k = 0; k < Kk; ++k) acc[k] += b[k][j] * wv;
  }
  #pragma unroll
  for (int k = 0; k < Kk; ++k) h2out[k * Hh + c] = fmaxf(acc[k] + g2b[c], 0.f);
}

// scores = softmax(relu(ht@centers^T)); clu = scores@h2; gated blend. 1 block/row.
__global__ __launch_bounds__(256) void finalk(
    const float* __restrict__ hfin, const float* __restrict__ cent,
    const float* __restrict__ h2, const float* __restrict__ w1w,
    const float* __restrict__ w1b, const float* __restrict__ w2w,
    const float* __restrict__ w2b, float* __restrict__ out)
{
  __shared__ alignas(16) float cs[Kk][Hh];
  __shared__ alignas(16) float hs[Kk][Hh];
  __shared__ float red[4];
  const int tid = threadIdx.x, lane = tid & 63, w = tid >> 6;
  const int n = blockIdx.x;
  for (int i = tid; i < Kk * Hh; i += 256) { ((float*)cs)[i] = cent[i]; ((float*)hs)[i] = h2[i]; }
  float ht = hfin[(size_t)n * Hh + tid];
  __syncthreads();

  auto bred = [&](float v) -> float {
    #pragma unroll
    for (int m = 1; m < 64; m <<= 1) v += __shfl_xor(v, m, 64);
    __syncthreads();
    if (lane == 0) red[w] = v;
    __syncthreads();
    return red[0] + red[1] + red[2] + red[3];
  };

  float ev[Kk];
  #pragma unroll
  for (int k = 0; k < Kk; ++k)
    ev[k] = fmaxf(bred(ht * cs[k][tid]), 0.f);

  float mx = ev[0];
  #pragma unroll
  for (int k = 1; k < Kk; ++k) mx = fmaxf(mx, ev[k]);
  float se = 0.f; float sc[Kk];
  #pragma unroll
  for (int k = 0; k < Kk; ++k) { sc[k] = expf(ev[k] - mx); se += sc[k]; }
  float inv = 1.f / se;
  float clu = 0.f;
  #pragma unroll
  for (int k = 0; k < Kk; ++k) clu += sc[k] * inv * hs[k][tid];

  float r1 = bred(clu * w1w[tid]);
  float r2 = bred(ht * w2w[tid]);
  float a1 = sigm(r1 + w1b[0]);
  float a2 = sigm(r2 + w2b[0]);
  float wn = a1 / (a1 + a2);
  out[(size_t)n * Hh + tid] = wn * clu + (1.f - wn) * ht;
}

// ---------------------------------------------------------------------------
// Host-side threefry2x32 (JAX), reproducing jax.random.permutation(key(42), 2048)[:12].
static void tf2x32(uint32_t k0, uint32_t k1, uint32_t c0, uint32_t c1,
                   uint32_t& o0, uint32_t& o1) {
  uint32_t ks2 = k0 ^ k1 ^ 0x1BD11BDAu;
  uint32_t x0 = c0 + k0, x1 = c1 + k1;
#define TFR(r) do { x0 += x1; x1 = (x1 << (r)) | (x1 >> (32 - (r))); x1 ^= x0; } while (0)
  TFR(13); TFR(15); TFR(26); TFR(6);
  x0 += k1;  x1 += ks2 + 1u;
  TFR(17); TFR(29); TFR(16); TFR(24);
  x0 += ks2; x1 += k0 + 2u;
  TFR(13); TFR(15); TFR(26); TFR(6);
  x0 += k0;  x1 += k1 + 3u;
  TFR(17); TFR(29); TFR(16); TFR(24);
  x0 += k1;  x1 += ks2 + 4u;
  TFR(13); TFR(15); TFR(26); TFR(6);
  x0 += ks2; x1 += k0 + 5u;
#undef TFR
  o0 = x0; o1 = x1;
}

static void compute_idx(int* out12) {
  uint32_t kh = 0u, kl = 42u;     // jax.random.key(42) -> (0, 42)
  std::vector<int> perm(Nn);
  for (int i = 0; i < Nn; ++i) perm[i] = i;
  std::vector<uint32_t> bits(Nn);
  std::vector<int> pos(Nn);
  for (int round = 0; round < 2; ++round) {     // 2 rounds for n=2048
    uint32_t nh, nl, sh, sl;
    tf2x32(kh, kl, 0u, 0u, nh, nl);             // split: counters (0,0),(0,1)
    tf2x32(kh, kl, 0u, 1u, sh, sl);
    kh = nh; kl = nl;
    // partitionable random_bits(32): bits[i] = o0 ^ o1 at counter (0, i)
    for (uint32_t i = 0; i < (uint32_t)Nn; ++i) {
      uint32_t o0, o1; tf2x32(sh, sl, 0u, i, o0, o1); bits[i] = o0 ^ o1;
    }
    for (int i = 0; i < Nn; ++i) pos[i] = i;
    std::stable_sort(pos.begin(), pos.end(),
                     [&](int a, int b) { return bits[a] < bits[b]; });
    std::vector<int> np(Nn);
    for (int i = 0; i < Nn; ++i) np[i] = perm[pos[i]];
    perm.swap(np);
  }
  for (int k = 0; k < Kk; ++k) out12[k] = perm[k];
}

// ---------------------------------------------------------------------------
extern "C" void kernel_launch(void* const* d_in, const int* in_sizes, int n_in,
                              void* d_out, int out_size, void* d_ws, size_t ws_size,
                              hipStream_t stream) {
  const float* x   = (const float*)d_in[0];
  const int*   len = (const int*)d_in[1];
  const float* Wih = (const float*)d_in[2];
  const float* Whh = (const float*)d_in[3];
  const float* bih = (const float*)d_in[4];
  const float* bhh = (const float*)d_in[5];
  const float* w1w = (const float*)d_in[6];
  const float* w1b = (const float*)d_in[7];
  const float* w2w = (const float*)d_in[8];
  const float* w2b = (const float*)d_in[9];
  const float* g1w = (const float*)d_in[10];
  const float* g1b = (const float*)d_in[11];
  const float* g2w = (const float*)d_in[12];
  const float* g2b = (const float*)d_in[13];
  float* out = (float*)d_out;

  float* wsf  = (float*)d_ws;
  float* hfin = wsf;                           // N*H
  float* cent = hfin + (size_t)Nn * Hh;        // K*H
  float* h2g  = cent + Kk * Hh;                // K*H
  float* part = h2g + Kk * Hh;                 // 2 * 16*K*H (parity dbuf)
  int*   pcnt = (int*)(part + 2 * 16 * Kk * Hh); // 2 * 16*K ints (pad 1024)
  int*   gflag = pcnt + 1024;                  // MAXIT ints
  float* pkw  = (float*)(gflag + 128);         // 393216 floats, 16B-aligned

  IdxArgs ia;
  compute_idx(ia.v);                           // host, deterministic, capture-safe

  pack_w<<<768, 64, 0, stream>>>(Wih, Whh, pkw);
  gru_q<<<256, 512, 0, stream>>>(x, len, pkw, bih, bhh, hfin);

  {
    void* ka[] = {(void*)&hfin, (void*)&cent, (void*)&part, (void*)&pcnt,
                  (void*)&gflag, (void*)&ia};
    hipLaunchCooperativeKernel((const void*)km_coop, dim3(16), dim3(1024),
                               ka, 0, stream);
  }

  gcn<<<1, 256, 0, stream>>>(cent, g1w, g1b, g2w, g2b, h2g);
  finalk<<<Nn, 256, 0, stream>>>(hfin, cent, h2g, w1w, w1b, w2w, w2b, out);
}